// Round 10
// baseline (1092.406 us; speedup 1.0000x reference)
//
#include <hip/hip_runtime.h>
#include <hip/hip_bf16.h>
#include <math.h>

#define BB 4
#define TT 1024
#define FF 1024
#define DIM 1024
#define NH 16
#define HD 64
#define MROWS (BB * TT)   // 4096
#define FB (FF / 64)      // 16 uint64 mask words per row
#define NBLK 768
#define NTHR (NBLK * 256) // 196608

typedef __attribute__((ext_vector_type(8))) short short8;
typedef __attribute__((ext_vector_type(4))) short short4v;
typedef __attribute__((ext_vector_type(4))) float f32x4;
typedef __hip_bfloat16 bf16;

__device__ __forceinline__ void async_copy16(const void* g, void* l) {
    __builtin_amdgcn_global_load_lds((const __attribute__((address_space(1))) void*)g,
                                     (__attribute__((address_space(3))) void*)l,
                                     16, 0, 0);
}

struct MegaArgs {
    const float* X_to; const float* X_from; const int* mask;
    const float* Wq; const float* bq;
    const float* Wk; const float* bk;
    const float* Wv; const float* bv;
    const float* Wo; const float* bo;
    float* out;
    bf16 *Xt16, *Xf16, *Wq16, *Wv16, *Wk16, *Wo16, *Q16, *K16, *Vt16;
    unsigned long long* Mb;
    unsigned* bar;   // 3 barrier counters, zeroed by init kernel
};

__global__ void init_bar(unsigned* bar) {
    if (threadIdx.x < 8) bar[threadIdx.x] = 0u;
}

// Device-scope grid barrier. All NBLK blocks are co-resident by construction
// (LDS 50432 B -> exactly 3 blocks/CU -> 768 slots = grid size).
// Bounded spin: on co-residency failure this fails fast instead of hanging.
__device__ __forceinline__ void grid_barrier(unsigned* cnt) {
    __syncthreads();
    __threadfence();                    // release phase writes (agent scope)
    if (threadIdx.x == 0) {
        __atomic_fetch_add(cnt, 1u, __ATOMIC_RELEASE);
        long spin = 0;
        while (__hip_atomic_load(cnt, __ATOMIC_ACQUIRE,
                                 __HIP_MEMORY_SCOPE_AGENT) < NBLK) {
            __builtin_amdgcn_s_sleep(8);
            if (++spin > 40000000L) break;   // fail-fast escape
        }
    }
    __syncthreads();
    __threadfence();                    // acquire side for all threads
}

// LDS: phase B staging As/Bs (16K) + epilogue overlay (17.4K);
//      phase C Ks(16K)+Vts(16K)+Pt(17.4K)+ls(256B) = 50432 B total;
//      phase D staging (12K) + f32 overlay (17.4K).
union SmemU {
    struct { bf16 As[128 * 32]; bf16 Bs[128 * 32]; } bst;
    bf16 Cs_b[64 * 136];
    struct { bf16 Ks[128 * 64]; bf16 Vts[64 * 128]; bf16 Pt[64 * 136]; float ls[64]; } at;
    struct { bf16 As[128 * 32]; bf16 Bs[64 * 32]; } dst;
    float Cs_f[64 * 68];
};

__global__ __launch_bounds__(256, 3) void mega_kernel(MegaArgs a) {
    __shared__ SmemU smem;

    const int tid  = threadIdx.x;
    const int bid  = blockIdx.x;
    const int lane = tid & 63;
    const int wave = tid >> 6;
    const int quad = lane >> 4;
    const int l16  = lane & 15;
    const int wbase = tid & ~63;

    // ======================= Phase A: convert + mask pack =================
    {
        const int gtid = bid * 256 + tid;
#pragma unroll 1
        for (int k = 0; k < 16; ++k) {
            int idx = gtid + k * NTHR;   // 16*NTHR == 3145728 float4s total
            const float* src; bf16* dst; int rel;
            if      (idx < 1048576) { src = a.X_to;   dst = a.Xt16; rel = idx; }
            else if (idx < 2097152) { src = a.X_from; dst = a.Xf16; rel = idx - 1048576; }
            else if (idx < 2359296) { src = a.Wq;     dst = a.Wq16; rel = idx - 2097152; }
            else if (idx < 2621440) { src = a.Wv;     dst = a.Wv16; rel = idx - 2359296; }
            else if (idx < 2883584) { src = a.Wk;     dst = a.Wk16; rel = idx - 2621440; }
            else                    { src = a.Wo;     dst = a.Wo16; rel = idx - 2883584; }
            float4 v = ((const float4*)src)[rel];
            union { bf16 t[4]; ushort4 u; } o;
            o.t[0] = __float2bfloat16(v.x);
            o.t[1] = __float2bfloat16(v.y);
            o.t[2] = __float2bfloat16(v.z);
            o.t[3] = __float2bfloat16(v.w);
            *(ushort4*)(dst + 4 * (size_t)rel) = o.u;
        }
        const int gw = (bid * 256 + tid) >> 6;
#pragma unroll 1
        for (int c = gw; c < BB * TT * FB; c += NBLK * 4) {
            int v = a.mask[(size_t)c * 64 + lane];
            unsigned long long bits = __ballot(v != 0);
            if (lane == 0) a.Mb[c] = bits;
        }
    }
    grid_barrier(a.bar + 0);

    // ======================= Phase B: QKV projections (R9 body) ===========
    {
        const int op  = bid >> 8;     // 0:Q 1:K 2:Vt
        const int idx = bid & 255;
        const bf16 *A, *W; const float* bias; bf16* C; int N, brow;
        if (op == 0)      { A = a.Xt16; W = a.Wq16; bias = a.bq; C = a.Q16;  N = DIM;   brow = 0; }
        else if (op == 1) { A = a.Xf16; W = a.Wv16; bias = a.bv; C = a.K16;  N = DIM;   brow = 0; }
        else              { A = a.Wk16; W = a.Xf16; bias = a.bk; C = a.Vt16; N = MROWS; brow = 1; }
        int m0, n0;
        if (brow) { m0 = (idx >> 5) * 128; n0 = (idx & 31) * 128; }
        else      { m0 = (idx >> 3) * 128; n0 = (idx & 7) * 128;  }

        bf16* As = smem.bst.As;
        bf16* Bs = smem.bst.Bs;
        const int wm = wave & 1;
        const int wn = wave >> 1;

        f32x4 acc[4][4] = {};

#pragma unroll 1
        for (int k0 = 0; k0 < DIM; k0 += 32) {
#pragma unroll
            for (int j = 0; j < 2; ++j) {
                int slot = j * 256 + tid;
                int r = slot >> 2;
                int g = (slot & 3) ^ (r & 3);
                async_copy16(A + (size_t)(m0 + r) * DIM + k0 + g * 8,
                             As + (size_t)(j * 256 + wbase) * 8);
                async_copy16(W + (size_t)(n0 + r) * DIM + k0 + g * 8,
                             Bs + (size_t)(j * 256 + wbase) * 8);
            }
            __syncthreads();

            short8 av[4], bv[4];
#pragma unroll
            for (int mi = 0; mi < 4; ++mi) {
                int r = wm * 64 + mi * 16 + l16;
                av[mi] = *(const short8*)(As + r * 32 + ((quad ^ (r & 3)) * 8));
            }
#pragma unroll
            for (int ni = 0; ni < 4; ++ni) {
                int r = wn * 64 + ni * 16 + l16;
                bv[ni] = *(const short8*)(Bs + r * 32 + ((quad ^ (r & 3)) * 8));
            }
#pragma unroll
            for (int mi = 0; mi < 4; ++mi)
#pragma unroll
                for (int ni = 0; ni < 4; ++ni)
                    acc[mi][ni] = __builtin_amdgcn_mfma_f32_16x16x32_bf16(
                        av[mi], bv[ni], acc[mi][ni], 0, 0, 0);
            __syncthreads();
        }

        bf16* Cs = smem.Cs_b;   // 64 x 136 overlay
#pragma unroll
        for (int half = 0; half < 2; ++half) {
            if (wm == half) {
#pragma unroll
                for (int ni = 0; ni < 4; ++ni) {
                    const int nl = wn * 64 + ni * 16 + l16;
                    float bcol = brow ? 0.0f : bias[n0 + nl];
#pragma unroll
                    for (int mi = 0; mi < 4; ++mi)
#pragma unroll
                        for (int i = 0; i < 4; ++i) {
                            const int mloc = mi * 16 + quad * 4 + i;
                            float v = acc[mi][ni][i] +
                                      (brow ? bias[m0 + half * 64 + mloc] : bcol);
                            Cs[mloc * 136 + nl] = __float2bfloat16(v);
                        }
                }
            }
            __syncthreads();
#pragma unroll
            for (int j = 0; j < 4; ++j) {
                int slot = j * 256 + tid;
                int rr = slot >> 4, cc = slot & 15;
                short8 v = *(const short8*)(Cs + rr * 136 + cc * 8);
                *(short8*)(C + (size_t)(m0 + half * 64 + rr) * N + n0 + cc * 8) = v;
            }
            __syncthreads();
        }
    }
    grid_barrier(a.bar + 1);

    // ======================= Phase C: attention (R7 body) =================
    {
        bf16*  Ks  = smem.at.Ks;
        bf16*  Vts = smem.at.Vts;
        bf16*  Pt  = smem.at.Pt;
        float* ls  = smem.at.ls;
        const int myrow = wave * 16 + l16;

#pragma unroll 1
        for (int tile = bid; tile < BB * NH * (TT / 64); tile += NBLK) {
            const int b  = tile >> 8;
            const int h  = (tile >> 4) & 15;
            const int t0 = (tile & 15) * 64;
            const size_t qrow0 = (size_t)b * TT + t0;
            const size_t krow0 = (size_t)b * FF;

            const bf16* qptr = a.Q16 + (qrow0 + myrow) * DIM + h * HD;
            short8 qb0 = *(const short8*)(qptr + quad * 8);
            short8 qb1 = *(const short8*)(qptr + 32 + quad * 8);

            const unsigned long long* mrow = a.Mb + (qrow0 + myrow) * FB;
            unsigned long long w0 = mrow[0];
            unsigned long long w1 = mrow[1];

            float lsum = 0.f;
            f32x4 oacc[4] = {};

#pragma unroll 1
            for (int it = 0; it < 8; ++it) {
                const int f0 = it * 128;
#pragma unroll
                for (int j = 0; j < 4; ++j) {
                    int slot = j * 256 + tid;
                    int rk = slot >> 3;
                    int gk = (slot & 7) ^ (rk & 7);
                    async_copy16(a.K16 + (krow0 + f0 + rk) * DIM + h * HD + gk * 8,
                                 Ks + (size_t)(j * 256 + wbase) * 8);
                    int rv = slot >> 4;
                    int gv = (slot & 15) ^ (rv & 15);
                    async_copy16(a.Vt16 + (size_t)(h * HD + rv) * MROWS + b * FF + f0 + gv * 8,
                                 Vts + (size_t)(j * 256 + wbase) * 8);
                }
                unsigned long long nw0 = 0, nw1 = 0;
                if (it < 7) { nw0 = mrow[2 * it + 2]; nw1 = mrow[2 * it + 3]; }
                __syncthreads();

                f32x4 sacc[8];
#pragma unroll
                for (int ft = 0; ft < 8; ++ft) {
                    int r = ft * 16 + l16;
                    short8 ka0 = *(const short8*)(Ks + r * 64 + ((quad       ^ (r & 7)) * 8));
                    short8 ka1 = *(const short8*)(Ks + r * 64 + (((quad + 4) ^ (r & 7)) * 8));
                    f32x4 s = {};
                    s = __builtin_amdgcn_mfma_f32_16x16x32_bf16(ka0, qb0, s, 0, 0, 0);
                    s = __builtin_amdgcn_mfma_f32_16x16x32_bf16(ka1, qb1, s, 0, 0, 0);
                    sacc[ft] = s;
                }

#pragma unroll
                for (int ft = 0; ft < 8; ++ft) {
                    const unsigned long long word = (ft < 4) ? w0 : w1;
                    const unsigned bits4 =
                        (unsigned)(word >> ((ft & 3) * 16 + quad * 4)) & 0xFu;
                    union { short4v v; short s[4]; } pk;
                    float psum = 0.f;
#pragma unroll
                    for (int i = 0; i < 4; ++i) {
                        float p = (bits4 >> i) & 1u ? __expf(sacc[ft][i] * 0.125f) : 0.f;
                        psum += p;
                        pk.s[i] = (short)__bfloat16_as_ushort(__float2bfloat16(p));
                    }
                    lsum += psum;
                    *(short4v*)(Pt + myrow * 136 + ft * 16 + quad * 4) = pk.v;
                }
                w0 = nw0; w1 = nw1;

                short8 pa[4];
#pragma unroll
                for (int kf = 0; kf < 4; ++kf)
                    pa[kf] = *(const short8*)(Pt + myrow * 136 + kf * 32 + quad * 8);
#pragma unroll
                for (int nt = 0; nt < 4; ++nt) {
                    int rd = nt * 16 + l16;
#pragma unroll
                    for (int kf = 0; kf < 4; ++kf) {
                        int g = (kf * 4 + quad) ^ (rd & 15);
                        short8 vb = *(const short8*)(Vts + rd * 128 + g * 8);
                        oacc[nt] = __builtin_amdgcn_mfma_f32_16x16x32_bf16(pa[kf], vb, oacc[nt], 0, 0, 0);
                    }
                }
                __syncthreads();
            }

            lsum += __shfl_xor(lsum, 16);
            lsum += __shfl_xor(lsum, 32);
            if (quad == 0) ls[myrow] = lsum;

#pragma unroll
            for (int i = 0; i < 4; ++i) {
                float inv = 1.0f / ls[wave * 16 + quad * 4 + i];
                const int prow = wave * 16 + quad * 4 + i;
#pragma unroll
                for (int nt = 0; nt < 4; ++nt)
                    Pt[prow * 136 + nt * 16 + l16] = __float2bfloat16(oacc[nt][i] * inv);
            }
            __syncthreads();
#pragma unroll
            for (int j = 0; j < 2; ++j) {
                int s = j * 256 + tid;
                int rr = s >> 3, off = (s & 7) * 8;
                short8 v = *(const short8*)(Pt + rr * 136 + off);
                *(short8*)(a.Q16 + (qrow0 + rr) * DIM + h * HD + off) = v;  // in place
            }
        }
    }
    grid_barrier(a.bar + 2);

    // ======================= Phase D: O-projection (R9 body) ==============
    if (bid < 512) {
        const int n0 = (bid & 15) * 64;
        const int m0 = (bid >> 4) * 128;
        bf16* As = smem.dst.As;
        bf16* Bs = smem.dst.Bs;
        const int wm = wave & 1;
        const int wn = wave >> 1;

        f32x4 acc[4][2] = {};

#pragma unroll 1
        for (int k0 = 0; k0 < DIM; k0 += 32) {
#pragma unroll
            for (int j = 0; j < 2; ++j) {
                int slot = j * 256 + tid;
                int r = slot >> 2;
                int g = (slot & 3) ^ (r & 3);
                async_copy16(a.Q16 + (size_t)(m0 + r) * DIM + k0 + g * 8,
                             As + (size_t)(j * 256 + wbase) * 8);
            }
            {
                int r = tid >> 2;
                int g = (tid & 3) ^ (r & 3);
                async_copy16(a.Wo16 + (size_t)(n0 + r) * DIM + k0 + g * 8,
                             Bs + (size_t)wbase * 8);
            }
            __syncthreads();

            short8 av[4], bv[2];
#pragma unroll
            for (int mi = 0; mi < 4; ++mi) {
                int r = wm * 64 + mi * 16 + l16;
                av[mi] = *(const short8*)(As + r * 32 + ((quad ^ (r & 3)) * 8));
            }
#pragma unroll
            for (int ni = 0; ni < 2; ++ni) {
                int r = wn * 32 + ni * 16 + l16;
                bv[ni] = *(const short8*)(Bs + r * 32 + ((quad ^ (r & 3)) * 8));
            }
#pragma unroll
            for (int mi = 0; mi < 4; ++mi)
#pragma unroll
                for (int ni = 0; ni < 2; ++ni)
                    acc[mi][ni] = __builtin_amdgcn_mfma_f32_16x16x32_bf16(
                        av[mi], bv[ni], acc[mi][ni], 0, 0, 0);
            __syncthreads();
        }

        float* Cs = smem.Cs_f;   // 64 x 68 overlay
#pragma unroll
        for (int half = 0; half < 2; ++half) {
            if (wm == half) {
#pragma unroll
                for (int ni = 0; ni < 2; ++ni) {
                    const int nl = wn * 32 + ni * 16 + l16;
                    const float bcol = a.bo[n0 + nl];
#pragma unroll
                    for (int mi = 0; mi < 4; ++mi)
#pragma unroll
                        for (int i = 0; i < 4; ++i) {
                            const int mloc = mi * 16 + quad * 4 + i;
                            Cs[mloc * 68 + nl] = acc[mi][ni][i] + bcol;
                        }
                }
            }
            __syncthreads();
#pragma unroll
            for (int j = 0; j < 4; ++j) {
                int slot = j * 256 + tid;
                int rr = slot >> 4, cc = slot & 15;
                float4 v = *(const float4*)(Cs + rr * 68 + cc * 4);
                *(float4*)(a.out + (size_t)(m0 + half * 64 + rr) * DIM + n0 + cc * 4) = v;
            }
            __syncthreads();
        }
    }
}

// ---------------------------------------------------------------------------
extern "C" void kernel_launch(void* const* d_in, const int* in_sizes, int n_in,
                              void* d_out, int out_size, void* d_ws, size_t ws_size,
                              hipStream_t stream) {
    char* ws = (char*)d_ws;

    MegaArgs a;
    a.X_to   = (const float*)d_in[0];
    a.X_from = (const float*)d_in[1];
    a.mask   = (const int*)  d_in[2];
    a.Wq = (const float*)d_in[3];  a.bq = (const float*)d_in[4];
    a.Wk = (const float*)d_in[5];  a.bk = (const float*)d_in[6];
    a.Wv = (const float*)d_in[7];  a.bv = (const float*)d_in[8];
    a.Wo = (const float*)d_in[9];  a.bo = (const float*)d_in[10];
    a.out = (float*)d_out;
    a.Xt16 = (bf16*)(ws);
    a.Xf16 = (bf16*)(ws + (8u  << 20));
    a.Wq16 = (bf16*)(ws + (16u << 20));
    a.Wv16 = (bf16*)(ws + (18u << 20));
    a.Wk16 = (bf16*)(ws + (20u << 20));
    a.Wo16 = (bf16*)(ws + (22u << 20));
    a.Q16  = (bf16*)(ws + (24u << 20));   // attn out overwrites in place
    a.K16  = (bf16*)(ws + (32u << 20));
    a.Vt16 = (bf16*)(ws + (40u << 20));   // [DIM][MROWS]
    a.Mb   = (unsigned long long*)(ws + (48u << 20));
    a.bar  = (unsigned*)(ws + (48u << 20) + (512u << 10));

    init_bar<<<1, 64, 0, stream>>>(a.bar);
    mega_kernel<<<NBLK, 256, 0, stream>>>(a);
}